// Round 6
// baseline (350.251 us; speedup 1.0000x reference)
//
#include <hip/hip_runtime.h>
#include <math.h>

// Problem constants (fixed by the reference)
#define Bn   32
#define Cn   256
#define Kn   3
#define HWn  4096      // 64*64
#define HW4n 1024      // HW in float4 units
#define BN_EPS 1e-5f
#define SPC  16        // channels per strip
#define NSTRIP (Cn / SPC)        // 16
#define BLOCKS_PER_B (NSTRIP*2)  // 32 blocks cover one batch sample

typedef float f4 __attribute__((ext_vector_type(4)));

// ---------------------------------------------------------------------------
// Single fused kernel, per-batch software barrier (plain launch, graph-safe).
// R6 barrier-hygiene fix vs R4 (181 us, VALUBusy 2% -> invalidate storm):
//  - spin polls with RELAXED agent loads (no per-poll cache invalidate)
//  - gap is read post-barrier with RELAXED agent-scope atomic loads
//    (coherent-point reads; no acquire fence -> local L2 keeps x warm)
//  - stencil xm/xc prefetched BEFORE the barrier (own L2-warm lines)
// Phases:
//  A) block reduces its OWN (b, 16ch, 512-f4) region; atomicAdd into gap
//  B) t0: release fetch_add cnt[b]; relaxed-spin until all 32 blocks of b
//     arrive. Grid fully co-resident (4 blocks/CU, capacity >=8) -> no
//     deadlock regardless of dispatch order.
//  C) 48 filter coeffs (4-way split-K over C=256), BN+sigmoid+gamma/beta
//     folded into a0/a1/a2.
//  D) 3-tap channel stencil, rolling register window, 2 px/thread, plain
//     stores (R5: store flavor is perf-neutral). Reads hit the local L2
//     warmed by phase A on the SAME CU.
// Reflect edges: c==0 uses x[1]; c==C-1 uses x[C-2].
// ---------------------------------------------------------------------------
__global__ __launch_bounds__(256) void fused_kernel(
        const float* __restrict__ x, const float* __restrict__ conv_w,
        const float* __restrict__ bn_w, const float* __restrict__ bn_b,
        const float* __restrict__ bn_mean, const float* __restrict__ bn_var,
        const float* __restrict__ gamma, const float* __restrict__ beta,
        float* __restrict__ out, float* __restrict__ gap,
        unsigned int* __restrict__ cnt) {
    const int blk   = blockIdx.x;
    const int half  = blk & 1;                     // which 512-f4 chunk of HW4
    const int strip = (blk >> 1) & (NSTRIP - 1);
    const int b     = blk >> 5;
    const int c0    = strip * SPC;
    const int t     = threadIdx.x;

    const f4* px = (const f4*)x;

    // ---- Phase A: partial GAP over own region --------------------------
    {
        const int ch = t >> 4;                     // 0..15 channel in strip
        const int l  = t & 15;                     // lane within channel group
        const size_t abase = (size_t)b * Cn * HW4n + (size_t)(c0 + ch) * HW4n
                           + (size_t)half * 512 + l;
        float s = 0.f;
#pragma unroll
        for (int j = 0; j < 32; ++j) {             // 32 independent f4 loads
            f4 v = px[abase + (size_t)j * 16];
            s += (v.x + v.y) + (v.z + v.w);
        }
        s += __shfl_down(s, 8, 16);
        s += __shfl_down(s, 4, 16);
        s += __shfl_down(s, 2, 16);
        s += __shfl_down(s, 1, 16);
        if (l == 0) atomicAdd(&gap[b * Cn + c0 + ch], s * (1.0f / (float)HWn));
    }

    // ---- prefetch stencil first loads (independent of the barrier;
    // ---- these are this block's own phase-A lines -> local L2 hits)
    const size_t base0 = (size_t)b * Cn * HW4n + (size_t)half * 512 + t;
    const size_t base1 = base0 + 256;
    const int cm = (c0 == 0) ? 1 : c0 - 1;         // reflect at c=0
    f4 xm0 = px[base0 + (size_t)cm * HW4n];
    f4 xm1 = px[base1 + (size_t)cm * HW4n];
    f4 xc0 = px[base0 + (size_t)c0 * HW4n];
    f4 xc1 = px[base1 + (size_t)c0 * HW4n];

    // __syncthreads drains vmcnt -> this block's atomics have reached the
    // coherent point before t0 publishes arrival.
    __syncthreads();
    if (t == 0) {
        __hip_atomic_fetch_add(&cnt[b], 1u, __ATOMIC_RELEASE,
                               __HIP_MEMORY_SCOPE_AGENT);
        unsigned int v;
        do {
            __builtin_amdgcn_s_sleep(8);
            v = __hip_atomic_load(&cnt[b], __ATOMIC_RELAXED,
                                  __HIP_MEMORY_SCOPE_AGENT);  // no invalidate
        } while (v < BLOCKS_PER_B);
    }
    __syncthreads();

    // ---- Phase C: 48 filter coefficients, 4-way split-K ----------------
    // gap read as relaxed agent-scope atomics: bypass L1/L2, read the same
    // coherent point the producer atomicAdds landed at. No cache invalidate.
    __shared__ __align__(16) float gap_s[Cn];
    __shared__ float a0s[SPC], a1s[SPC], a2s[SPC];
    gap_s[t] = __hip_atomic_load(&gap[b * Cn + t], __ATOMIC_RELAXED,
                                 __HIP_MEMORY_SCOPE_AGENT);
    __syncthreads();
    if (t < 192) {
        const int ol = t >> 2, p = t & 3;          // ol = k*16+cc
        const int k = ol >> 4, cc = ol & 15;
        const int c = c0 + cc;
        const int o = k * Cn + c;
        const f4* w4 = (const f4*)(conv_w + (size_t)o * Cn) + p * 16;
        const f4* g4 = ((const f4*)gap_s) + p * 16;
        float acc = 0.f;
#pragma unroll
        for (int i = 0; i < 16; ++i) {
            f4 g = g4[i], w = w4[i];
            acc += g.x * w.x + g.y * w.y + g.z * w.z + g.w * w.w;
        }
        acc += __shfl_down(acc, 2, 4);
        acc += __shfl_down(acc, 1, 4);
        if (p == 0) {
            float fv = (acc - bn_mean[o]) * rsqrtf(bn_var[o] + BN_EPS) * bn_w[o] + bn_b[o];
            float sg = 1.0f / (1.0f + expf(-fv));
            float a  = (k == 1) ? (sg * gamma[c] + beta[c]) : (sg * gamma[c]);
            if (k == 0) a0s[cc] = a; else if (k == 1) a1s[cc] = a; else a2s[cc] = a;
        }
    }
    __syncthreads();

    // ---- Phase D: rolling register window stencil, 2 px/thread ----------
    f4* pout = (f4*)out;
#pragma unroll 4
    for (int i = 0; i < SPC; ++i) {
        const int c   = c0 + i;
        const int cnn = (c == Cn - 1) ? (Cn - 2) : (c + 1);  // reflect at c=C-1
        f4 xn0 = px[base0 + (size_t)cnn * HW4n];
        f4 xn1 = px[base1 + (size_t)cnn * HW4n];
        const float a0 = a0s[i], a1 = a1s[i], a2 = a2s[i];
        f4 o0, o1;
        o0.x = fmaf(a0, xm0.x, fmaf(a1, xc0.x, a2 * xn0.x));
        o0.y = fmaf(a0, xm0.y, fmaf(a1, xc0.y, a2 * xn0.y));
        o0.z = fmaf(a0, xm0.z, fmaf(a1, xc0.z, a2 * xn0.z));
        o0.w = fmaf(a0, xm0.w, fmaf(a1, xc0.w, a2 * xn0.w));
        o1.x = fmaf(a0, xm1.x, fmaf(a1, xc1.x, a2 * xn1.x));
        o1.y = fmaf(a0, xm1.y, fmaf(a1, xc1.y, a2 * xn1.y));
        o1.z = fmaf(a0, xm1.z, fmaf(a1, xc1.z, a2 * xn1.z));
        o1.w = fmaf(a0, xm1.w, fmaf(a1, xc1.w, a2 * xn1.w));
        pout[base0 + (size_t)c * HW4n] = o0;
        pout[base1 + (size_t)c * HW4n] = o1;
        xm0 = xc0; xc0 = xn0;
        xm1 = xc1; xc1 = xn1;
    }
}

extern "C" void kernel_launch(void* const* d_in, const int* in_sizes, int n_in,
                              void* d_out, int out_size, void* d_ws, size_t ws_size,
                              hipStream_t stream) {
    const float* x       = (const float*)d_in[0];
    const float* conv_w  = (const float*)d_in[1];
    const float* bn_w    = (const float*)d_in[2];
    const float* bn_b    = (const float*)d_in[3];
    const float* bn_mean = (const float*)d_in[4];
    const float* bn_var  = (const float*)d_in[5];
    const float* gamma   = (const float*)d_in[6];
    const float* beta    = (const float*)d_in[7];
    float* out = (float*)d_out;

    float* gap        = (float*)d_ws;                     // [B*C] = 32 KiB
    unsigned int* cnt = (unsigned int*)(gap + Bn * Cn);   // [B]   = 128 B

    // zero accumulators + barrier counters (graph-capturable async memset)
    hipMemsetAsync(d_ws, 0, Bn * Cn * sizeof(float) + Bn * sizeof(unsigned int),
                   stream);

    fused_kernel<<<Bn * BLOCKS_PER_B, 256, 0, stream>>>(
        x, conv_w, bn_w, bn_b, bn_mean, bn_var, gamma, beta, out, gap, cnt);
}

// Round 7
// 264.089 us; speedup vs baseline: 1.3263x; 1.3263x over previous
//
#include <hip/hip_runtime.h>
#include <math.h>

// Problem constants (fixed by the reference)
#define Bn   32
#define Cn   256
#define Kn   3
#define HWn  4096      // 64*64
#define HW4n 1024      // HW in float4 units
#define BN_EPS 1e-5f
#define SPC  8         // channels per strip (R7: was 16 -> doubles blocks/CU)
#define NSTRIP (Cn / SPC)   // 32

typedef float f4 __attribute__((ext_vector_type(4)));

// ---------------------------------------------------------------------------
// Kernel 1: global average pool. One block per (b,c); 256 threads each read
// 4 float4 (16 floats) -> block reduce -> gap[b*C+c].
// Normal (caching) loads on purpose: this pass warms x into Infinity Cache
// (x = 128 MiB, L3 = 256 MiB -> fully resident) for the stencil pass.
// ---------------------------------------------------------------------------
__global__ __launch_bounds__(256) void gap_kernel(const float* __restrict__ x,
                                                  float* __restrict__ gap) {
    const int bc = blockIdx.x;                     // b*Cn + c
    const f4* px = (const f4*)(x + (size_t)bc * HWn);
    const int t = threadIdx.x;
    float s = 0.f;
#pragma unroll
    for (int i = 0; i < 4; ++i) {
        f4 v = px[t + i * 256];
        s += (v.x + v.y) + (v.z + v.w);
    }
    // wave64 shuffle reduce
#pragma unroll
    for (int off = 32; off > 0; off >>= 1) s += __shfl_down(s, off, 64);
    __shared__ float ls[4];
    const int wave = t >> 6, lane = t & 63;
    if (lane == 0) ls[wave] = s;
    __syncthreads();
    if (t == 0) {
        gap[bc] = (ls[0] + ls[1] + ls[2] + ls[3]) * (1.0f / (float)HWn);
    }
}

// ---------------------------------------------------------------------------
// Kernel 2 (fused filt + stencil). R7 experiment: SPC 16->8, grid 1024->2048
// blocks, __launch_bounds__(256,8) pins VGPR<=64 -> 8 blocks/CU = 32 waves/CU
// AND 2 px/thread. Every prior variant held waves x px/thread constant
// (R2: 32w x 1px; R3/R5: 16w x 2px — equal, both ~80 us). This doubles
// total outstanding memory ops per CU; if the stencil is MLP/latency-bound
// (VALUBusy ~2% for this loop in the R4/R6 fused kernel), time drops.
//  - first xm/xc loads issued before the filter phase (in flight across it)
//  - filter: 24 outputs (k=0..2, cc=0..7), 8-way split-K over C=256,
//    BN(eval)+sigmoid+gamma/beta folded into a0/a1/a2
//  - stencil: rolling register window over 8 channels, 2 px/thread,
//    plain stores (R5: flavor-neutral).
// Reflect edges: c==0 uses x[1]; c==C-1 uses x[C-2].
// ---------------------------------------------------------------------------
__global__ __launch_bounds__(256, 8) void stencil_kernel(
        const float* __restrict__ x, const float* __restrict__ gap,
        const float* __restrict__ conv_w,
        const float* __restrict__ bn_w, const float* __restrict__ bn_b,
        const float* __restrict__ bn_mean, const float* __restrict__ bn_var,
        const float* __restrict__ gamma, const float* __restrict__ beta,
        float* __restrict__ out) {
    const int blk   = blockIdx.x;
    const int half  = blk & 1;                     // which 512-f4 chunk of HW4
    const int strip = (blk >> 1) & (NSTRIP - 1);   // 0..31
    const int b     = blk >> 6;                    // 64 blocks per batch
    const int c0    = strip * SPC;
    const int t     = threadIdx.x;

    // ---- issue first stencil loads early; in flight across filter phase
    const f4* px = (const f4*)x;
    const size_t base0 = (size_t)b * Cn * HW4n + (size_t)half * 512 + t;
    const size_t base1 = base0 + 256;
    const int cm = (c0 == 0) ? 1 : c0 - 1;         // reflect at c=0
    f4 xm0 = px[base0 + (size_t)cm * HW4n];
    f4 xm1 = px[base1 + (size_t)cm * HW4n];
    f4 xc0 = px[base0 + (size_t)c0 * HW4n];
    f4 xc1 = px[base1 + (size_t)c0 * HW4n];

    // ---- filter phase: 24 outputs (k=0..2, cc=0..7), 8-way split-K ------
    __shared__ __align__(16) float gap_s[Cn];
    __shared__ float a0s[SPC], a1s[SPC], a2s[SPC];
    gap_s[t] = gap[b * Cn + t];
    __syncthreads();
    if (t < 192) {
        const int ol = t >> 3, p = t & 7;          // ol = k*8+cc, p = K-slice
        const int k = ol >> 3, cc = ol & 7;
        const int c = c0 + cc;
        const int o = k * Cn + c;
        const f4* w4 = (const f4*)(conv_w + (size_t)o * Cn) + p * 8;
        const f4* g4 = ((const f4*)gap_s) + p * 8;
        float acc = 0.f;
#pragma unroll
        for (int i = 0; i < 8; ++i) {
            f4 g = g4[i], w = w4[i];
            acc += g.x * w.x + g.y * w.y + g.z * w.z + g.w * w.w;
        }
        acc += __shfl_down(acc, 4, 8);
        acc += __shfl_down(acc, 2, 8);
        acc += __shfl_down(acc, 1, 8);
        if (p == 0) {
            float fv = (acc - bn_mean[o]) * rsqrtf(bn_var[o] + BN_EPS) * bn_w[o] + bn_b[o];
            float sg = 1.0f / (1.0f + expf(-fv));
            float a  = (k == 1) ? (sg * gamma[c] + beta[c]) : (sg * gamma[c]);
            if (k == 0) a0s[cc] = a; else if (k == 1) a1s[cc] = a; else a2s[cc] = a;
        }
    }
    __syncthreads();

    // ---- stencil phase: rolling register window, 2 pixels/thread --------
    f4* pout = (f4*)out;
#pragma unroll
    for (int i = 0; i < SPC; ++i) {
        const int c   = c0 + i;
        const int cnn = (c == Cn - 1) ? (Cn - 2) : (c + 1);  // reflect at c=C-1
        f4 xn0 = px[base0 + (size_t)cnn * HW4n];
        f4 xn1 = px[base1 + (size_t)cnn * HW4n];
        const float a0 = a0s[i], a1 = a1s[i], a2 = a2s[i];
        f4 o0, o1;
        o0.x = fmaf(a0, xm0.x, fmaf(a1, xc0.x, a2 * xn0.x));
        o0.y = fmaf(a0, xm0.y, fmaf(a1, xc0.y, a2 * xn0.y));
        o0.z = fmaf(a0, xm0.z, fmaf(a1, xc0.z, a2 * xn0.z));
        o0.w = fmaf(a0, xm0.w, fmaf(a1, xc0.w, a2 * xn0.w));
        o1.x = fmaf(a0, xm1.x, fmaf(a1, xc1.x, a2 * xn1.x));
        o1.y = fmaf(a0, xm1.y, fmaf(a1, xc1.y, a2 * xn1.y));
        o1.z = fmaf(a0, xm1.z, fmaf(a1, xc1.z, a2 * xn1.z));
        o1.w = fmaf(a0, xm1.w, fmaf(a1, xc1.w, a2 * xn1.w));
        pout[base0 + (size_t)c * HW4n] = o0;
        pout[base1 + (size_t)c * HW4n] = o1;
        xm0 = xc0; xc0 = xn0;
        xm1 = xc1; xc1 = xn1;
    }
}

extern "C" void kernel_launch(void* const* d_in, const int* in_sizes, int n_in,
                              void* d_out, int out_size, void* d_ws, size_t ws_size,
                              hipStream_t stream) {
    const float* x       = (const float*)d_in[0];
    const float* conv_w  = (const float*)d_in[1];
    const float* bn_w    = (const float*)d_in[2];
    const float* bn_b    = (const float*)d_in[3];
    const float* bn_mean = (const float*)d_in[4];
    const float* bn_var  = (const float*)d_in[5];
    const float* gamma   = (const float*)d_in[6];
    const float* beta    = (const float*)d_in[7];
    float* out = (float*)d_out;

    float* gap = (float*)d_ws;            // [B*C] = 32 KiB

    gap_kernel<<<Bn * Cn, 256, 0, stream>>>(x, gap);
    stencil_kernel<<<(Bn * NSTRIP * 2), 256, 0, stream>>>(
        x, gap, conv_w, bn_w, bn_b, bn_mean, bn_var, gamma, beta, out);
}